// Round 1
// baseline (275.456 us; speedup 1.0000x reference)
//
#include <hip/hip_runtime.h>
#include <hip/hip_bf16.h>

// Problem constants: B=2, N=2048, D=512, H=8, hd=64
typedef __bf16 bf16x8 __attribute__((ext_vector_type(8)));
typedef float f32x4 __attribute__((ext_vector_type(4)));

__device__ __forceinline__ unsigned short f2bu(float f) {
    __hip_bfloat16 h = __float2bfloat16(f);
    unsigned short u;
    __builtin_memcpy(&u, &h, 2);
    return u;
}

// async global->LDS, 16B per lane. LDS base must be wave-uniform; HW appends lane*16.
#define GLDS16(gp, lp) __builtin_amdgcn_global_load_lds( \
    (const __attribute__((address_space(1))) unsigned int*)(gp), \
    (__attribute__((address_space(3))) unsigned int*)(lp), 16, 0, 0)

// ---- workspace layout (bytes) ----
#define OFF_XB  0u                          // x as bf16            4096*512*2 = 4 MB
#define OFF_WT  (OFF_XB + 4194304u)         // W_q/k/v transposed   3*512*512*2 = 1.5 MB
#define OFF_QS  (OFF_WT + 1572864u)         // Q*(1/8) bf16         4 MB
#define OFF_KB  (OFF_QS + 4194304u)         // K bf16               4 MB
#define OFF_VB  (OFF_KB + 4194304u)         // V bf16               4 MB
#define OFF_VT  (OFF_VB + 4194304u)         // V^T [b,h,d,n] bf16   4 MB
#define OFF_CV  (OFF_VT + 4194304u)         // c[b,n] f32           16 KB

// ---------------- prep: x (f32) -> bf16 ----------------
__global__ void k_convert_x(const float* __restrict__ x, unsigned short* __restrict__ xb) {
    int i = blockIdx.x * blockDim.x + threadIdx.x;   // over float4 groups, 2M/4
    float4 v = reinterpret_cast<const float4*>(x)[i];
    ushort4 o;
    o.x = f2bu(v.x); o.y = f2bu(v.y); o.z = f2bu(v.z); o.w = f2bu(v.w);
    reinterpret_cast<ushort4*>(xb)[i] = o;
}

// ---------------- prep: Wt[n][k] = bf16(W[k][n]) for q,k,v ----------------
__global__ void k_wt(const float* __restrict__ w0, const float* __restrict__ w1,
                     const float* __restrict__ w2, unsigned short* __restrict__ wt) {
    int z = blockIdx.x;
    int k0 = (blockIdx.y >> 3) * 64, n0 = (blockIdx.y & 7) * 64;
    const float* W = (z == 0) ? w0 : ((z == 1) ? w1 : w2);
    __shared__ float T[64][65];
    int c = threadIdx.x & 63, r0 = threadIdx.x >> 6;
#pragma unroll
    for (int i = 0; i < 16; i++) { int r = r0 + i * 4; T[r][c] = W[(k0 + r) * 512 + n0 + c]; }
    __syncthreads();
    unsigned short* Wt = wt + z * (512 * 512);
#pragma unroll
    for (int i = 0; i < 16; i++) { int a = r0 + i * 4; Wt[(n0 + a) * 512 + k0 + c] = f2bu(T[c][a]); }
}

// ---------------- prep: c[b,n] = x[b,n,:] @ w_g[D:] ----------------
__global__ void k_cvec(const float* __restrict__ x, const float* __restrict__ wg,
                       float* __restrict__ cv) {
    int row = blockIdx.x * 4 + (threadIdx.x >> 6);  // 4096 rows
    int l = threadIdx.x & 63;
    const float* xr = x + (size_t)row * 512;
    float s = 0.f;
#pragma unroll
    for (int d = 0; d < 512; d += 64) s += xr[d + l] * wg[512 + d + l];
#pragma unroll
    for (int off = 32; off >= 1; off >>= 1) s += __shfl_xor(s, off, 64);
    if (l == 0) cv[row] = s;
}

// ---------------- fused QKV projection GEMM (128x128 tile, bf16 MFMA) ----------------
__global__ __launch_bounds__(256) void k_gemm(
    const unsigned short* __restrict__ xb, const unsigned short* __restrict__ wt,
    const float* __restrict__ bq, const float* __restrict__ bk, const float* __restrict__ bv,
    unsigned short* __restrict__ Qs, unsigned short* __restrict__ Kb,
    unsigned short* __restrict__ Vb) {
    __shared__ __align__(16) unsigned short As[128 * 32];
    __shared__ __align__(16) unsigned short Bs[128 * 32];
    int z = blockIdx.z;
    const unsigned short* Wt = wt + z * (512 * 512);
    const float* bias = (z == 0) ? bq : ((z == 1) ? bk : bv);
    unsigned short* Cout = (z == 0) ? Qs : ((z == 1) ? Kb : Vb);
    float scale = (z == 0) ? 0.125f : 1.0f;   // Q pre-scaled by 1/sqrt(64)
    int m0 = blockIdx.x * 128, n0 = blockIdx.y * 128;
    int tid = threadIdx.x, w = tid >> 6, l = tid & 63;
    int q = l >> 4, cl = l & 15;
    f32x4 acc[4][4];
#pragma unroll
    for (int mt = 0; mt < 4; mt++)
#pragma unroll
        for (int nt = 0; nt < 4; nt++)
#pragma unroll
            for (int r = 0; r < 4; r++) acc[mt][nt][r] = 0.f;

    int arow = w * 32 + (l >> 2);
    int achunk = (l & 3) * 8;
    for (int k0 = 0; k0 < 512; k0 += 32) {
#pragma unroll
        for (int e = 0; e < 2; e++) {
            GLDS16(xb + (m0 + arow + e * 16) * 512 + k0 + achunk, As + w * 1024 + e * 512);
            GLDS16(Wt + (n0 + arow + e * 16) * 512 + k0 + achunk, Bs + w * 1024 + e * 512);
        }
        __syncthreads();
        bf16x8 af[4], bfr[4];
#pragma unroll
        for (int mt = 0; mt < 4; mt++)
            af[mt] = *reinterpret_cast<const bf16x8*>(As + (64 * (w >> 1) + 16 * mt + cl) * 32 + q * 8);
#pragma unroll
        for (int nt = 0; nt < 4; nt++)
            bfr[nt] = *reinterpret_cast<const bf16x8*>(Bs + (64 * (w & 1) + 16 * nt + cl) * 32 + q * 8);
#pragma unroll
        for (int mt = 0; mt < 4; mt++)
#pragma unroll
            for (int nt = 0; nt < 4; nt++)
                acc[mt][nt] = __builtin_amdgcn_mfma_f32_16x16x32_bf16(af[mt], bfr[nt], acc[mt][nt], 0, 0, 0);
        __syncthreads();
    }
#pragma unroll
    for (int nt = 0; nt < 4; nt++) {
        int col = n0 + 64 * (w & 1) + 16 * nt + cl;
        float bv_ = bias[col];
#pragma unroll
        for (int mt = 0; mt < 4; mt++) {
#pragma unroll
            for (int r = 0; r < 4; r++) {
                int row = m0 + 64 * (w >> 1) + 16 * mt + 4 * q + r;
                Cout[row * 512 + col] = f2bu((acc[mt][nt][r] + bv_) * scale);
            }
        }
    }
}

// ---------------- V -> V^T  ([b,h,d,n] so PV B-fragments are contiguous) ----------------
__global__ void k_vt(const unsigned short* __restrict__ Vb, unsigned short* __restrict__ Vt) {
    int s = blockIdx.y;            // s = b*8 + h
    int b = s >> 3, h = s & 7;
    int n0 = blockIdx.x * 64;
    __shared__ unsigned short T[64][66];
    int c = threadIdx.x & 63, r0 = threadIdx.x >> 6;
#pragma unroll
    for (int i = 0; i < 16; i++) {
        int r = r0 + i * 4;
        T[r][c] = Vb[(b * 2048 + n0 + r) * 512 + h * 64 + c];
    }
    __syncthreads();
#pragma unroll
    for (int i = 0; i < 16; i++) {
        int a = r0 + i * 4;
        Vt[(s * 64 + a) * 2048 + n0 + c] = T[c][a];
    }
}

// ---------------- flash attention: scores + soul bias + log(adj) + softmax + PV + residual ----------------
__global__ __launch_bounds__(256) void k_attn(
    const unsigned short* __restrict__ Qs, const unsigned short* __restrict__ Kb,
    const unsigned short* __restrict__ Vt, const float* __restrict__ adj,
    const float* __restrict__ cvec, const float* __restrict__ x, float* __restrict__ out) {
    __shared__ __align__(16) unsigned short P[4][16 * 72];  // per-wave P tile, stride 72
    int bid = blockIdx.x;
    int it = bid & 31, h = (bid >> 5) & 7, b = bid >> 8;
    int i0 = it * 64;
    int tid = threadIdx.x, w = tid >> 6, l = tid & 63, q = l >> 4, cl = l & 15;

    // Q fragments (A-layout: m = cl, k = 32*kk + q*8 + j), already scaled by 1/8
    bf16x8 qf0, qf1;
    {
        const unsigned short* qp = Qs + (b * 2048 + i0 + w * 16 + cl) * 512 + h * 64 + q * 8;
        qf0 = *reinterpret_cast<const bf16x8*>(qp);
        qf1 = *reinterpret_cast<const bf16x8*>(qp + 32);
    }
    f32x4 O[4];
    float m_i[4], l_i[4];
#pragma unroll
    for (int nt = 0; nt < 4; nt++)
#pragma unroll
        for (int r = 0; r < 4; r++) O[nt][r] = 0.f;
#pragma unroll
    for (int r = 0; r < 4; r++) { m_i[r] = -INFINITY; l_i[r] = 0.f; }

    const float* adjr = adj + ((size_t)(b * 2048 + i0 + w * 16 + q * 4)) * 2048;
    unsigned short* pw = &P[w][0];

    for (int j0 = 0; j0 < 2048; j0 += 64) {
        // S = (Q/8) K^T  (C/D layout: row = q*4+r, col = cl, per 16-col tile nt)
        f32x4 S[4];
#pragma unroll
        for (int nt = 0; nt < 4; nt++) {
#pragma unroll
            for (int r = 0; r < 4; r++) S[nt][r] = 0.f;
            const unsigned short* kp = Kb + (b * 2048 + j0 + 16 * nt + cl) * 512 + h * 64 + q * 8;
            bf16x8 kf0 = *reinterpret_cast<const bf16x8*>(kp);
            bf16x8 kf1 = *reinterpret_cast<const bf16x8*>(kp + 32);
            S[nt] = __builtin_amdgcn_mfma_f32_16x16x32_bf16(qf0, kf0, S[nt], 0, 0, 0);
            S[nt] = __builtin_amdgcn_mfma_f32_16x16x32_bf16(qf1, kf1, S[nt], 0, 0, 0);
        }
        // + c[j] + log(adj[i,j] + eps)   (a[i] + b_g cancels in softmax)
#pragma unroll
        for (int nt = 0; nt < 4; nt++) {
            float cv = cvec[b * 2048 + j0 + 16 * nt + cl];
#pragma unroll
            for (int r = 0; r < 4; r++) {
                float ad = adjr[(size_t)r * 2048 + j0 + 16 * nt + cl];
                S[nt][r] += cv + __logf(ad + 1e-9f);
            }
        }
        // online softmax (rows live in 16-lane quads)
        float alpha[4], rs[4];
#pragma unroll
        for (int r = 0; r < 4; r++) {
            float t = fmaxf(fmaxf(S[0][r], S[1][r]), fmaxf(S[2][r], S[3][r]));
#pragma unroll
            for (int m = 8; m >= 1; m >>= 1) t = fmaxf(t, __shfl_xor(t, m, 64));
            float mn = fmaxf(m_i[r], t);
            alpha[r] = __expf(m_i[r] - mn);
            m_i[r] = mn;
            rs[r] = 0.f;
        }
#pragma unroll
        for (int nt = 0; nt < 4; nt++)
#pragma unroll
            for (int r = 0; r < 4; r++) {
                float p = __expf(S[nt][r] - m_i[r]);
                S[nt][r] = p;
                rs[r] += p;
            }
#pragma unroll
        for (int r = 0; r < 4; r++) {
            float t = rs[r];
#pragma unroll
            for (int m = 8; m >= 1; m >>= 1) t += __shfl_xor(t, m, 64);
            l_i[r] = l_i[r] * alpha[r] + t;
#pragma unroll
            for (int nt = 0; nt < 4; nt++) O[nt][r] *= alpha[r];
        }
        // P: C/D layout -> A layout via per-wave LDS
#pragma unroll
        for (int nt = 0; nt < 4; nt++)
#pragma unroll
            for (int r = 0; r < 4; r++)
                pw[(q * 4 + r) * 72 + 16 * nt + cl] = f2bu(S[nt][r]);
        __syncthreads();
        bf16x8 pf0 = *reinterpret_cast<const bf16x8*>(pw + cl * 72 + q * 8);
        bf16x8 pf1 = *reinterpret_cast<const bf16x8*>(pw + cl * 72 + 32 + q * 8);
        // O += P V  (V^T layout makes B-fragments contiguous)
#pragma unroll
        for (int nt = 0; nt < 4; nt++) {
            const unsigned short* vp = Vt + ((b * 8 + h) * 64 + 16 * nt + cl) * 2048 + j0 + q * 8;
            bf16x8 vf0 = *reinterpret_cast<const bf16x8*>(vp);
            bf16x8 vf1 = *reinterpret_cast<const bf16x8*>(vp + 32);
            O[nt] = __builtin_amdgcn_mfma_f32_16x16x32_bf16(pf0, vf0, O[nt], 0, 0, 0);
            O[nt] = __builtin_amdgcn_mfma_f32_16x16x32_bf16(pf1, vf1, O[nt], 0, 0, 0);
        }
    }
    // epilogue: normalize + residual
#pragma unroll
    for (int r = 0; r < 4; r++) {
        float inv = 1.0f / l_i[r];
        int row = b * 2048 + i0 + w * 16 + q * 4 + r;
#pragma unroll
        for (int nt = 0; nt < 4; nt++) {
            int idx = row * 512 + h * 64 + 16 * nt + cl;
            out[idx] = O[nt][r] * inv + x[idx];
        }
    }
}

extern "C" void kernel_launch(void* const* d_in, const int* in_sizes, int n_in,
                              void* d_out, int out_size, void* d_ws, size_t ws_size,
                              hipStream_t stream) {
    const float* x   = (const float*)d_in[0];
    const float* adj = (const float*)d_in[1];
    const float* Wq  = (const float*)d_in[2];
    const float* bq  = (const float*)d_in[3];
    const float* Wk  = (const float*)d_in[4];
    const float* bk  = (const float*)d_in[5];
    const float* Wv  = (const float*)d_in[6];
    const float* bv  = (const float*)d_in[7];
    const float* wg  = (const float*)d_in[8];
    // d_in[9] (b_g) unused: row-constant bias cancels in softmax
    float* out = (float*)d_out;
    char* ws = (char*)d_ws;
    unsigned short* xb = (unsigned short*)(ws + OFF_XB);
    unsigned short* wt = (unsigned short*)(ws + OFF_WT);
    unsigned short* Qs = (unsigned short*)(ws + OFF_QS);
    unsigned short* Kb = (unsigned short*)(ws + OFF_KB);
    unsigned short* Vb = (unsigned short*)(ws + OFF_VB);
    unsigned short* Vt = (unsigned short*)(ws + OFF_VT);
    float* cv = (float*)(ws + OFF_CV);

    k_convert_x<<<2048, 256, 0, stream>>>(x, xb);
    k_wt<<<dim3(3, 64), 256, 0, stream>>>(Wq, Wk, Wv, wt);
    k_cvec<<<1024, 256, 0, stream>>>(x, wg, cv);
    k_gemm<<<dim3(32, 4, 3), 256, 0, stream>>>(xb, wt, bq, bk, bv, Qs, Kb, Vb);
    k_vt<<<dim3(32, 16), 256, 0, stream>>>(Vb, Vt);
    k_attn<<<512, 256, 0, stream>>>(Qs, Kb, Vt, adj, cv, x, out);
}

// Round 2
// 187.406 us; speedup vs baseline: 1.4698x; 1.4698x over previous
//
#include <hip/hip_runtime.h>
#include <hip/hip_bf16.h>

// Problem constants: B=2, N=2048, D=512, H=8, hd=64
typedef __bf16 bf16x8 __attribute__((ext_vector_type(8)));
typedef float f32x4 __attribute__((ext_vector_type(4)));

#define LOG2E 1.44269504f

__device__ __forceinline__ unsigned short f2bu(float f) {
    __hip_bfloat16 h = __float2bfloat16(f);
    unsigned short u;
    __builtin_memcpy(&u, &h, 2);
    return u;
}

__device__ __forceinline__ float fexp2(float x) {
#if __has_builtin(__builtin_amdgcn_exp2f)
    return __builtin_amdgcn_exp2f(x);
#else
    return __expf(x * 0.69314718f);
#endif
}

// async global->LDS, 16B per lane. LDS base must be wave-uniform; HW appends lane*16.
#define GLDS16(gp, lp) __builtin_amdgcn_global_load_lds( \
    (const __attribute__((address_space(1))) unsigned int*)(gp), \
    (__attribute__((address_space(3))) unsigned int*)(lp), 16, 0, 0)

// ---- workspace layout (bytes) ----
#define OFF_XB  0u                          // x as bf16            4096*512*2 = 4 MB
#define OFF_WT  (OFF_XB + 4194304u)         // W_q/k/v transposed   3*512*512*2 = 1.5 MB
#define OFF_QS  (OFF_WT + 1572864u)         // Q*(0.125*log2e) bf16 4 MB
#define OFF_KB  (OFF_QS + 4194304u)         // K bf16               4 MB
#define OFF_VB  (OFF_KB + 4194304u)         // V bf16               4 MB
#define OFF_VT  (OFF_VB + 4194304u)         // V^T [b,h,d,n] bf16   4 MB
#define OFF_CV  (OFF_VT + 4194304u)         // cv[b,n] f32 ((c-8)*log2e)  16 KB

// ---------------- prep: x->bf16 AND cv[row] = (x@wg[D:] - 8)*log2e ----------------
__global__ void k_prep(const float* __restrict__ x, const float* __restrict__ wg,
                       unsigned short* __restrict__ xb, float* __restrict__ cv) {
    int row = blockIdx.x * 4 + (threadIdx.x >> 6);   // 4096 rows
    int l = threadIdx.x & 63;
    const float4* xr = reinterpret_cast<const float4*>(x + (size_t)row * 512);
    float4 a = xr[l * 2], b2 = xr[l * 2 + 1];
    ushort4 o0, o1;
    o0.x = f2bu(a.x);  o0.y = f2bu(a.y);  o0.z = f2bu(a.z);  o0.w = f2bu(a.w);
    o1.x = f2bu(b2.x); o1.y = f2bu(b2.y); o1.z = f2bu(b2.z); o1.w = f2bu(b2.w);
    ushort4* dst = reinterpret_cast<ushort4*>(xb + (size_t)row * 512);
    dst[l * 2] = o0; dst[l * 2 + 1] = o1;
    const float4* wr = reinterpret_cast<const float4*>(wg + 512);
    float4 g0 = wr[l * 2], g1 = wr[l * 2 + 1];
    float s = a.x * g0.x + a.y * g0.y + a.z * g0.z + a.w * g0.w
            + b2.x * g1.x + b2.y * g1.y + b2.z * g1.z + b2.w * g1.w;
#pragma unroll
    for (int off = 32; off >= 1; off >>= 1) s += __shfl_xor(s, off, 64);
    if (l == 0) cv[row] = (s - 8.0f) * LOG2E;   // fixed-M=8 folded in, log2e pre-scaled
}

// ---------------- prep: Wt[n][k] = bf16(W[k][n]) for q,k,v ----------------
__global__ void k_wt(const float* __restrict__ w0, const float* __restrict__ w1,
                     const float* __restrict__ w2, unsigned short* __restrict__ wt) {
    int z = blockIdx.x;
    int k0 = (blockIdx.y >> 3) * 64, n0 = (blockIdx.y & 7) * 64;
    const float* W = (z == 0) ? w0 : ((z == 1) ? w1 : w2);
    __shared__ float T[64][65];
    int c = threadIdx.x & 63, r0 = threadIdx.x >> 6;
#pragma unroll
    for (int i = 0; i < 16; i++) { int r = r0 + i * 4; T[r][c] = W[(k0 + r) * 512 + n0 + c]; }
    __syncthreads();
    unsigned short* Wt = wt + z * (512 * 512);
#pragma unroll
    for (int i = 0; i < 16; i++) { int a = r0 + i * 4; Wt[(n0 + a) * 512 + k0 + c] = f2bu(T[c][a]); }
}

// ---------------- fused QKV projection GEMM (128x128 tile, bf16 MFMA) ----------------
__global__ __launch_bounds__(256) void k_gemm(
    const unsigned short* __restrict__ xb, const unsigned short* __restrict__ wt,
    const float* __restrict__ bq, const float* __restrict__ bk, const float* __restrict__ bv,
    unsigned short* __restrict__ Qs, unsigned short* __restrict__ Kb,
    unsigned short* __restrict__ Vb) {
    __shared__ __align__(16) unsigned short As[128 * 32];
    __shared__ __align__(16) unsigned short Bs[128 * 32];
    int z = blockIdx.z;
    const unsigned short* Wt = wt + z * (512 * 512);
    const float* bias = (z == 0) ? bq : ((z == 1) ? bk : bv);
    unsigned short* Cout = (z == 0) ? Qs : ((z == 1) ? Kb : Vb);
    float scale = (z == 0) ? (0.125f * LOG2E) : 1.0f;   // Q pre-scaled by log2e/sqrt(64)
    int m0 = blockIdx.x * 128, n0 = blockIdx.y * 128;
    int tid = threadIdx.x, w = tid >> 6, l = tid & 63;
    int q = l >> 4, cl = l & 15;
    f32x4 acc[4][4];
#pragma unroll
    for (int mt = 0; mt < 4; mt++)
#pragma unroll
        for (int nt = 0; nt < 4; nt++)
#pragma unroll
            for (int r = 0; r < 4; r++) acc[mt][nt][r] = 0.f;

    int arow = w * 32 + (l >> 2);
    int achunk = (l & 3) * 8;
    for (int k0 = 0; k0 < 512; k0 += 32) {
#pragma unroll
        for (int e = 0; e < 2; e++) {
            GLDS16(xb + (m0 + arow + e * 16) * 512 + k0 + achunk, As + w * 1024 + e * 512);
            GLDS16(Wt + (n0 + arow + e * 16) * 512 + k0 + achunk, Bs + w * 1024 + e * 512);
        }
        __syncthreads();
        bf16x8 af[4], bfr[4];
#pragma unroll
        for (int mt = 0; mt < 4; mt++)
            af[mt] = *reinterpret_cast<const bf16x8*>(As + (64 * (w >> 1) + 16 * mt + cl) * 32 + q * 8);
#pragma unroll
        for (int nt = 0; nt < 4; nt++)
            bfr[nt] = *reinterpret_cast<const bf16x8*>(Bs + (64 * (w & 1) + 16 * nt + cl) * 32 + q * 8);
#pragma unroll
        for (int mt = 0; mt < 4; mt++)
#pragma unroll
            for (int nt = 0; nt < 4; nt++)
                acc[mt][nt] = __builtin_amdgcn_mfma_f32_16x16x32_bf16(af[mt], bfr[nt], acc[mt][nt], 0, 0, 0);
        __syncthreads();
    }
#pragma unroll
    for (int nt = 0; nt < 4; nt++) {
        int col = n0 + 64 * (w & 1) + 16 * nt + cl;
        float bv_ = bias[col];
#pragma unroll
        for (int mt = 0; mt < 4; mt++) {
#pragma unroll
            for (int r = 0; r < 4; r++) {
                int row = m0 + 64 * (w >> 1) + 16 * mt + 4 * q + r;
                Cout[row * 512 + col] = f2bu((acc[mt][nt][r] + bv_) * scale);
            }
        }
    }
}

// ---------------- V -> V^T  ([b,h,d,n] so PV B-fragments are contiguous) ----------------
__global__ void k_vt(const unsigned short* __restrict__ Vb, unsigned short* __restrict__ Vt) {
    int s = blockIdx.y;            // s = b*8 + h
    int b = s >> 3, h = s & 7;
    int n0 = blockIdx.x * 64;
    __shared__ unsigned short T[64][66];
    int c = threadIdx.x & 63, r0 = threadIdx.x >> 6;
#pragma unroll
    for (int i = 0; i < 16; i++) {
        int r = r0 + i * 4;
        T[r][c] = Vb[(b * 2048 + n0 + r) * 512 + h * 64 + c];
    }
    __syncthreads();
#pragma unroll
    for (int i = 0; i < 16; i++) {
        int a = r0 + i * 4;
        Vt[(s * 64 + a) * 2048 + n0 + c] = T[c][a];
    }
}

// ---------------- flash attention, fixed-max variant ----------------
// block = (b, it) x h; 4 waves: rh = w>>1 (32-row chunk), jh = w&1 (j-half).
// Each wave: 32 i-rows x 1024 j-cols, 16 j-tiles of 64. No barrier in loop.
// p = exp2(qk*log2e/8 + cv[j]) * (adj+eps); O,l combine across jh at the end.
__global__ __launch_bounds__(256) void k_attn(
    const unsigned short* __restrict__ Qs, const unsigned short* __restrict__ Kb,
    const unsigned short* __restrict__ Vt, const float* __restrict__ adj,
    const float* __restrict__ cvec, const float* __restrict__ x, float* __restrict__ out) {
    __shared__ __align__(16) unsigned short P[4][32 * 72];   // per-wave P tile (32 rows x 64, stride 72)
    __shared__ float Ocomb[2][2][4][4][64];                  // [rh][rc][nt][r][lane]
    __shared__ float Lcomb[2][2][4][64];                     // [rh][rc][r][lane]
    int bid = blockIdx.x;
    // bid = h*64 + (b*32 + it): the 8 h-blocks of one adjacency stripe share bid%8 -> same XCD L2
    int h = bid >> 6, s = bid & 63, b = s >> 5, it = s & 31;
    int i0 = it * 64;
    int tid = threadIdx.x, w = tid >> 6, l = tid & 63, q = l >> 4, cl = l & 15;
    int rh = w >> 1, jh = w & 1;
    int rowbase = i0 + rh * 32;

    // Q fragments for 2 row-chunks (A-layout: m=cl, k=q*8+j), pre-scaled by log2e/8
    bf16x8 qf[2][2];
#pragma unroll
    for (int rc = 0; rc < 2; rc++) {
        const unsigned short* qp = Qs + (size_t)(b * 2048 + rowbase + rc * 16 + cl) * 512 + h * 64 + q * 8;
        qf[rc][0] = *reinterpret_cast<const bf16x8*>(qp);
        qf[rc][1] = *reinterpret_cast<const bf16x8*>(qp + 32);
    }
    f32x4 O[2][4];
    float lsum[2][4];
#pragma unroll
    for (int rc = 0; rc < 2; rc++) {
#pragma unroll
        for (int nt = 0; nt < 4; nt++)
#pragma unroll
            for (int r = 0; r < 4; r++) O[rc][nt][r] = 0.f;
#pragma unroll
        for (int r = 0; r < 4; r++) lsum[rc][r] = 0.f;
    }

    const float* adjb = adj + ((size_t)(b * 2048 + rowbase + q * 4)) * 2048;
    const float* cvb = cvec + b * 2048;
    const unsigned short* Kh = Kb + (size_t)b * 2048 * 512 + h * 64;
    const unsigned short* Vh = Vt + ((size_t)(b * 8 + h) * 64) * 2048;
    unsigned short* pw = &P[w][0];
    int jbase0 = jh * 1024;

    // preload K tile t=0 (register double-buffer)
    bf16x8 kf[2][4][2];
#pragma unroll
    for (int nt = 0; nt < 4; nt++) {
        const unsigned short* kp = Kh + (size_t)(jbase0 + 16 * nt + cl) * 512 + q * 8;
        kf[0][nt][0] = *reinterpret_cast<const bf16x8*>(kp);
        kf[0][nt][1] = *reinterpret_cast<const bf16x8*>(kp + 32);
    }

#pragma unroll 2
    for (int t = 0; t < 16; t++) {
        int buf = t & 1;
        int jb = jbase0 + t * 64;
        // adjacency + cv loads for tile t (used mid-iter; issued first: longest latency)
        float af[2][4][4], cvf[4];
#pragma unroll
        for (int nt = 0; nt < 4; nt++) cvf[nt] = cvb[jb + 16 * nt + cl];
#pragma unroll
        for (int rc = 0; rc < 2; rc++)
#pragma unroll
            for (int nt = 0; nt < 4; nt++)
#pragma unroll
                for (int r = 0; r < 4; r++)
                    af[rc][nt][r] = adjb[(size_t)(rc * 16 + r) * 2048 + jb + 16 * nt + cl];
        // prefetch K tile t+1 (clamped at end; redundant last-iter load is harmless)
        {
            int jn = jbase0 + ((t < 15) ? (t + 1) : t) * 64;
#pragma unroll
            for (int nt = 0; nt < 4; nt++) {
                const unsigned short* kp = Kh + (size_t)(jn + 16 * nt + cl) * 512 + q * 8;
                kf[buf ^ 1][nt][0] = *reinterpret_cast<const bf16x8*>(kp);
                kf[buf ^ 1][nt][1] = *reinterpret_cast<const bf16x8*>(kp + 32);
            }
        }
        // V tile t (used at iter end)
        bf16x8 vf[4][2];
#pragma unroll
        for (int nt = 0; nt < 4; nt++) {
            const unsigned short* vp = Vh + (size_t)(16 * nt + cl) * 2048 + jb + q * 8;
            vf[nt][0] = *reinterpret_cast<const bf16x8*>(vp);
            vf[nt][1] = *reinterpret_cast<const bf16x8*>(vp + 32);
        }
        // S = (Q*log2e/8) K^T
        f32x4 S[2][4];
#pragma unroll
        for (int rc = 0; rc < 2; rc++)
#pragma unroll
            for (int nt = 0; nt < 4; nt++) {
#pragma unroll
                for (int r = 0; r < 4; r++) S[rc][nt][r] = 0.f;
                S[rc][nt] = __builtin_amdgcn_mfma_f32_16x16x32_bf16(qf[rc][0], kf[buf][nt][0], S[rc][nt], 0, 0, 0);
                S[rc][nt] = __builtin_amdgcn_mfma_f32_16x16x32_bf16(qf[rc][1], kf[buf][nt][1], S[rc][nt], 0, 0, 0);
            }
        // p = exp2(S + cv') * (adj + eps); accumulate per-lane row sums; stash p into S
#pragma unroll
        for (int rc = 0; rc < 2; rc++)
#pragma unroll
            for (int nt = 0; nt < 4; nt++)
#pragma unroll
                for (int r = 0; r < 4; r++) {
                    float e = fexp2(S[rc][nt][r] + cvf[nt]);
                    float p = e * (af[rc][nt][r] + 1e-9f);
                    S[rc][nt][r] = p;
                    lsum[rc][r] += p;
                }
        // P: C/D layout -> A layout via per-wave LDS (wave-local; no barrier needed)
#pragma unroll
        for (int rc = 0; rc < 2; rc++)
#pragma unroll
            for (int nt = 0; nt < 4; nt++)
#pragma unroll
                for (int r = 0; r < 4; r++)
                    pw[(rc * 16 + q * 4 + r) * 72 + 16 * nt + cl] = f2bu(S[rc][nt][r]);
        // O += P V
#pragma unroll
        for (int rc = 0; rc < 2; rc++) {
            bf16x8 pf0 = *reinterpret_cast<const bf16x8*>(pw + rc * 1152 + cl * 72 + q * 8);
            bf16x8 pf1 = *reinterpret_cast<const bf16x8*>(pw + rc * 1152 + cl * 72 + 32 + q * 8);
#pragma unroll
            for (int nt = 0; nt < 4; nt++) {
                O[rc][nt] = __builtin_amdgcn_mfma_f32_16x16x32_bf16(pf0, vf[nt][0], O[rc][nt], 0, 0, 0);
                O[rc][nt] = __builtin_amdgcn_mfma_f32_16x16x32_bf16(pf1, vf[nt][1], O[rc][nt], 0, 0, 0);
            }
        }
    }

    // combine j-halves (fixed-M: plain adds), reduce row sums, write out with residual
    if (jh == 1) {
#pragma unroll
        for (int rc = 0; rc < 2; rc++) {
#pragma unroll
            for (int nt = 0; nt < 4; nt++)
#pragma unroll
                for (int r = 0; r < 4; r++) Ocomb[rh][rc][nt][r][l] = O[rc][nt][r];
#pragma unroll
            for (int r = 0; r < 4; r++) Lcomb[rh][rc][r][l] = lsum[rc][r];
        }
    }
    __syncthreads();
    if (jh == 0) {
#pragma unroll
        for (int rc = 0; rc < 2; rc++) {
            float inv[4];
#pragma unroll
            for (int r = 0; r < 4; r++) {
                float t = lsum[rc][r] + Lcomb[rh][rc][r][l];
#pragma unroll
                for (int m = 8; m >= 1; m >>= 1) t += __shfl_xor(t, m, 64);
                inv[r] = 1.0f / t;
            }
#pragma unroll
            for (int nt = 0; nt < 4; nt++)
#pragma unroll
                for (int r = 0; r < 4; r++) {
                    float o = O[rc][nt][r] + Ocomb[rh][rc][nt][r][l];
                    int row = b * 2048 + rowbase + rc * 16 + q * 4 + r;
                    int idx = row * 512 + h * 64 + 16 * nt + cl;
                    out[idx] = o * inv[r] + x[idx];
                }
        }
    }
}

extern "C" void kernel_launch(void* const* d_in, const int* in_sizes, int n_in,
                              void* d_out, int out_size, void* d_ws, size_t ws_size,
                              hipStream_t stream) {
    const float* x   = (const float*)d_in[0];
    const float* adj = (const float*)d_in[1];
    const float* Wq  = (const float*)d_in[2];
    const float* bq  = (const float*)d_in[3];
    const float* Wk  = (const float*)d_in[4];
    const float* bk  = (const float*)d_in[5];
    const float* Wv  = (const float*)d_in[6];
    const float* bv  = (const float*)d_in[7];
    const float* wg  = (const float*)d_in[8];
    // d_in[9] (b_g) unused: row-constant bias cancels in softmax
    float* out = (float*)d_out;
    char* ws = (char*)d_ws;
    unsigned short* xb = (unsigned short*)(ws + OFF_XB);
    unsigned short* wt = (unsigned short*)(ws + OFF_WT);
    unsigned short* Qs = (unsigned short*)(ws + OFF_QS);
    unsigned short* Kb = (unsigned short*)(ws + OFF_KB);
    unsigned short* Vb = (unsigned short*)(ws + OFF_VB);
    unsigned short* Vt = (unsigned short*)(ws + OFF_VT);
    float* cv = (float*)(ws + OFF_CV);

    k_prep<<<1024, 256, 0, stream>>>(x, wg, xb, cv);
    k_wt<<<dim3(3, 64), 256, 0, stream>>>(Wq, Wk, Wv, wt);
    k_gemm<<<dim3(32, 4, 3), 256, 0, stream>>>(xb, wt, bq, bk, bv, Qs, Kb, Vb);
    k_vt<<<dim3(32, 16), 256, 0, stream>>>(Vb, Vt);
    k_attn<<<512, 256, 0, stream>>>(Qs, Kb, Vt, adj, cv, x, out);
}